// Round 1
// baseline (572.376 us; speedup 1.0000x reference)
//
#include <hip/hip_runtime.h>
#include <hip/hip_bf16.h>
#include <math.h>

// ---------------------------------------------------------------------------
// TransformerBlock: B=8 T=1024 C=1024 H=16 d=64, bf16 MFMA compute, fp32 acc.
// R6: QKV + FFN1 moved to 256x256 8-phase pipelined GEMM (counted vmcnt,
//     setprio, 16x16x32 MFMA, double-buffered 128KB LDS). Wo/FFN2 keep the
//     128x128 kernel; attn/LN/transposes unchanged.
// ---------------------------------------------------------------------------

#define DEVI __device__ __forceinline__

typedef __attribute__((ext_vector_type(4))) float floatx4;
typedef __attribute__((ext_vector_type(16))) float floatx16;
typedef __attribute__((ext_vector_type(8))) short shortx8;   // 8 bf16 = 4 VGPRs

DEVI ushort f2b(float f) {
    __hip_bfloat16 h = __float2bfloat16(f);
    return __builtin_bit_cast(ushort, h);
}

DEVI void gl_lds16(const ushort* g, ushort* l) {
    // 16B direct global->LDS. LDS dest = wave-uniform base + lane*16.
    __builtin_amdgcn_global_load_lds(
        (const __attribute__((address_space(1))) void*)g,
        (__attribute__((address_space(3))) void*)l, 16, 0, 0);
}

// tanh-form GeLU: |err| vs erf-GeLU ~3e-3 — far under the bf16 threshold.
DEVI float gelu_f(float v) {
    const float u0 = 0.7978845608f * v * (1.0f + 0.044715f * v * v);
    const float u  = fminf(fmaxf(u0, -15.0f), 15.0f);
    const float e  = exp2f(u * 2.885390082f);      // e^{2u}
    const float th = 1.0f - 2.0f / (e + 1.0f);     // tanh(u)
    return 0.5f * v * (1.0f + th);
}

// ---------------------------------------------------------------------------
// Fused transpose of the four 1024x1024 weights (z picks the matrix).
// ---------------------------------------------------------------------------
__global__ void transp4_kernel(const float* __restrict__ s0, const float* __restrict__ s1,
                               const float* __restrict__ s2, const float* __restrict__ s3,
                               ushort* __restrict__ d0, ushort* __restrict__ d1,
                               ushort* __restrict__ d2, ushort* __restrict__ d3) {
    const int z = blockIdx.z;
    const float* src = (z == 0) ? s0 : (z == 1) ? s1 : (z == 2) ? s2 : s3;
    ushort*      dst = (z == 0) ? d0 : (z == 1) ? d1 : (z == 2) ? d2 : d3;
    __shared__ float tile[32][33];
    const int c0 = blockIdx.x * 32, r0 = blockIdx.y * 32;
    const int tx = threadIdx.x, ty = threadIdx.y;   // 32 x 8
#pragma unroll
    for (int i = 0; i < 32; i += 8)
        tile[ty + i][tx] = src[(size_t)(r0 + ty + i) * 1024 + c0 + tx];
    __syncthreads();
#pragma unroll
    for (int i = 0; i < 32; i += 8)
        dst[(size_t)(c0 + ty + i) * 1024 + r0 + tx] = f2b(tile[tx][ty + i]);
}

__global__ void transp_kernel(const float* __restrict__ src,
                              ushort* __restrict__ dst, int R, int C) {
    __shared__ float tile[32][33];
    const int c0 = blockIdx.x * 32, r0 = blockIdx.y * 32;
    const int tx = threadIdx.x, ty = threadIdx.y;   // 32 x 8
#pragma unroll
    for (int i = 0; i < 32; i += 8)
        tile[ty + i][tx] = src[(size_t)(r0 + ty + i) * C + c0 + tx];
    __syncthreads();
#pragma unroll
    for (int i = 0; i < 32; i += 8)
        dst[(size_t)(c0 + ty + i) * R + r0 + tx] = f2b(tile[tx][ty + i]);
}

// ---------------------------------------------------------------------------
// LayerNorm over C=1024, one block (256 thr) per token. fp32 in, bf16 out.
// ---------------------------------------------------------------------------
__global__ __launch_bounds__(256)
void ln_kernel(const float* __restrict__ x, const float* __restrict__ w,
               const float* __restrict__ b, ushort* __restrict__ out) {
    __shared__ float red[8];
    const int m = blockIdx.x;
    const int tid = threadIdx.x;
    const float4 xv = *(const float4*)&x[(size_t)m * 1024 + tid * 4];
    float s  = xv.x + xv.y + xv.z + xv.w;
    float s2 = xv.x * xv.x + xv.y * xv.y + xv.z * xv.z + xv.w * xv.w;
#pragma unroll
    for (int o = 32; o >= 1; o >>= 1) {
        s  += __shfl_xor(s, o, 64);
        s2 += __shfl_xor(s2, o, 64);
    }
    const int wv_ = tid >> 6;
    if ((tid & 63) == 0) { red[wv_] = s; red[4 + wv_] = s2; }
    __syncthreads();
    s  = red[0] + red[1] + red[2] + red[3];
    s2 = red[4] + red[5] + red[6] + red[7];
    const float mu   = s * (1.0f / 1024.0f);
    const float var  = s2 * (1.0f / 1024.0f) - mu * mu;
    const float rstd = rsqrtf(var + 1e-5f);
    const float4 wv = *(const float4*)&w[tid * 4];
    const float4 bv = *(const float4*)&b[tid * 4];
    ushort o4[4];
    o4[0] = f2b((xv.x - mu) * rstd * wv.x + bv.x);
    o4[1] = f2b((xv.y - mu) * rstd * wv.y + bv.y);
    o4[2] = f2b((xv.z - mu) * rstd * wv.z + bv.z);
    o4[3] = f2b((xv.w - mu) * rstd * wv.w + bv.w);
    *(uint2*)&out[(size_t)m * 1024 + tid * 4] = *(uint2*)o4;
}

// ---------------------------------------------------------------------------
// 256x256 8-phase pipelined GEMM (T2+T3+T4+T5). 512 thr = 8 waves (2M x 4N),
// BK=64, double-buffered 128KB LDS, mfma_f32_16x16x32_bf16, acc[2][4][2][2].
// Per K-tile: 4 phases (mq,nq) = (0,0),(0,1),(1,1),(1,0); each phase stages
// one 16KB half-tile into a half that is provably dead:
//   p0 -> A1(j+1), p1 -> B0(j+1), p2 -> A0(j+2), p3 -> B1(j+2)
// Gate once per K-tile: s_waitcnt vmcnt(4) (2 half-tiles in flight) + barrier.
//   MODE 1: fused QKV (Q/K head layouts; V^T via post-loop LDS transpose)
//   MODE 3: bf16 out = gelu(acc + bias)
// ---------------------------------------------------------------------------

#define STAGE_A(j, h) { const int c_ = (j) & 1;                                         \
    gl_lds16(pA + (size_t)((h) * 128) * K + (j) * 64,                                   \
             lds + c_ * 16384 + (h) * 8192 + dOff);                                     \
    gl_lds16(pA + (size_t)((h) * 128 + 8) * K + (j) * 64,                               \
             lds + c_ * 16384 + (h) * 8192 + dOff + 512); }

#define STAGE_B(j, h) { const int c_ = (j) & 1;                                         \
    gl_lds16(pB + (size_t)((h) * 128) * K + (j) * 64,                                   \
             lds + 32768 + c_ * 16384 + (h) * 8192 + dOff);                             \
    gl_lds16(pB + (size_t)((h) * 128 + 8) * K + (j) * 64,                               \
             lds + 32768 + c_ * 16384 + (h) * 8192 + dOff + 512); }

#define LOAD_A(mq, c) { const ushort* ap = lds + (c) * 16384 + (mq) * 8192;             \
    _Pragma("unroll") for (int mi = 0; mi < 4; ++mi) {                                  \
        af[mi][0] = *(const shortx8*)&ap[aBase + mi * 1024];                            \
        af[mi][1] = *(const shortx8*)&ap[(aBase ^ 32) + mi * 1024]; } }

#define LOAD_B(nq, c) { const ushort* bp = lds + 32768 + (c) * 16384 + (nq) * 8192;     \
    _Pragma("unroll") for (int ni = 0; ni < 2; ++ni) {                                  \
        bf[ni][0] = *(const shortx8*)&bp[bBase + ni * 1024];                            \
        bf[ni][1] = *(const shortx8*)&bp[(bBase ^ 32) + ni * 1024]; } }

#define MFMA16(mq, nq) {                                                                \
    _Pragma("unroll") for (int mi = 0; mi < 4; ++mi)                                    \
    _Pragma("unroll") for (int ni = 0; ni < 2; ++ni)                                    \
    _Pragma("unroll") for (int ks = 0; ks < 2; ++ks)                                    \
        acc[mq][mi][nq][ni] = __builtin_amdgcn_mfma_f32_16x16x32_bf16(                  \
            af[mi][ks], bf[ni][ks], acc[mq][mi][nq][ni], 0, 0, 0); }

#define PH_SYNC() { __builtin_amdgcn_s_barrier();                                       \
    asm volatile("s_waitcnt lgkmcnt(0)" ::: "memory");                                  \
    __builtin_amdgcn_sched_barrier(0); }

template <int MODE>
__global__ __launch_bounds__(512, 2)
void gemm8(const ushort* __restrict__ A, const ushort* __restrict__ Bt,
           const float* __restrict__ biasQ, const float* __restrict__ biasK,
           const float* __restrict__ biasV,
           void* __restrict__ out, void* __restrict__ out2, void* __restrict__ out3,
           int N, int K) {
    __shared__ __align__(16) ushort lds[65536];   // 128 KB: sA[2][256x64] | sB[2][256x64]

    const int tid  = threadIdx.x;
    const int lane = tid & 63;
    const int w    = tid >> 6;       // 0..7
    const int wr   = w >> 2;         // 0..1  (M sub-tile)
    const int wc   = w & 3;          // 0..3  (N sub-tile)

    // XCD-aware bijective block swizzle (nwg % 8 == 0 for all our grids)
    int bx = blockIdx.x, by = blockIdx.y;
    {
        const int nwg = gridDim.x * gridDim.y;
        if ((nwg & 7) == 0) {
            const int flat = by * gridDim.x + bx;
            const int cpx  = nwg >> 3;
            const int wg   = (flat & 7) * cpx + (flat >> 3);
            bx = wg % gridDim.x;
            by = wg / gridDim.x;
        }
    }
    const int m0 = by * 256;
    const int n0 = bx * 256;
    const int NT = K >> 6;           // K-tiles of 64 (K=1024 -> 16)

    floatx4 acc[2][4][2][2] = {};    // [mq][mi][nq][ni]

    // ---- staging addresses (global source pre-swizzled, LDS dest linear) ----
    const int lr3 = lane >> 3;            // 0..7
    const int sc  = (lane & 7) ^ lr3;     // swizzled source col-block
    const ushort* pA = A  + (size_t)(m0 + w * 16 + lr3) * K + sc * 8;
    const ushort* pB = Bt + (size_t)(n0 + w * 16 + lr3) * K + sc * 8;
    const int dOff = w * 1024;            // ushort units; +512 for 2nd issue

    // ---- fragment read addresses (swizzled on read; r&7 == lane&7) ----
    const int c0    = (lane >> 4) ^ (lane & 7);
    const int aBase = (wr * 64 + (lane & 15)) * 64 + c0 * 8;
    const int bBase = (wc * 32 + (lane & 15)) * 64 + c0 * 8;

    shortx8 af[4][2], bf[2][2];

    // ---- prologue: tile 0 fully + A0/B1 of tile 1 (12 loads/thread) ----
    STAGE_A(0, 0); STAGE_B(0, 1); STAGE_A(0, 1); STAGE_B(0, 0);
    STAGE_A(1, 0); STAGE_B(1, 1);

#pragma unroll 1
    for (int j = 0; j < NT; ++j) {
        const int c = j & 1;
        // K-tile gate: everything except the last 2 half-tiles has landed.
        if (j == NT - 1) { asm volatile("s_waitcnt vmcnt(0)" ::: "memory"); }
        else             { asm volatile("s_waitcnt vmcnt(4)" ::: "memory"); }
        __builtin_amdgcn_s_barrier();

        // p0: (mq0, nq0) — reads A0,B0; stages A1(j+1) into other buffer
        LOAD_A(0, c); LOAD_B(0, c);
        if (j + 1 < NT) STAGE_A(j + 1, 1);
        PH_SYNC();
        __builtin_amdgcn_s_setprio(1); MFMA16(0, 0); __builtin_amdgcn_s_setprio(0);
        __builtin_amdgcn_s_barrier();

        // p1: (mq0, nq1) — reads A0,B1; stages B0(j+1)
        LOAD_B(1, c);
        if (j + 1 < NT) STAGE_B(j + 1, 0);
        PH_SYNC();
        __builtin_amdgcn_s_setprio(1); MFMA16(0, 1); __builtin_amdgcn_s_setprio(0);
        __builtin_amdgcn_s_barrier();

        // p2: (mq1, nq1) — reads A1,B1; stages A0(j+2) over dead A0 (this buf)
        LOAD_A(1, c);
        if (j + 2 < NT) STAGE_A(j + 2, 0);
        PH_SYNC();
        __builtin_amdgcn_s_setprio(1); MFMA16(1, 1); __builtin_amdgcn_s_setprio(0);
        __builtin_amdgcn_s_barrier();

        // p3: (mq1, nq0) — reads A1,B0; stages B1(j+2) over dead B1 (this buf)
        LOAD_B(0, c);
        if (j + 2 < NT) STAGE_B(j + 2, 1);
        PH_SYNC();
        __builtin_amdgcn_s_setprio(1); MFMA16(1, 0); __builtin_amdgcn_s_setprio(0);
        // no barrier here: the loop-head gate (vmcnt + barrier) closes the tile
    }

    // ---- epilogue. C/D map (16x16x32): row=(lane>>4)*4+reg, col=lane&15 ----
    if constexpr (MODE == 3) {
        float bvals[2][2];
#pragma unroll
        for (int nq = 0; nq < 2; ++nq)
#pragma unroll
            for (int ni = 0; ni < 2; ++ni)
                bvals[nq][ni] = biasQ[n0 + nq * 128 + wc * 32 + ni * 16 + (lane & 15)];
        ushort* o = (ushort*)out;
#pragma unroll
        for (int mq = 0; mq < 2; ++mq)
#pragma unroll
        for (int mi = 0; mi < 4; ++mi)
#pragma unroll
        for (int nq = 0; nq < 2; ++nq)
#pragma unroll
        for (int ni = 0; ni < 2; ++ni) {
            const int gm0 = m0 + mq * 128 + wr * 64 + mi * 16 + (lane >> 4) * 4;
            const int gn  = n0 + nq * 128 + wc * 32 + ni * 16 + (lane & 15);
#pragma unroll
            for (int r = 0; r < 4; ++r)
                o[(size_t)(gm0 + r) * N + gn] =
                    f2b(gelu_f(acc[mq][mi][nq][ni][r] + bvals[nq][ni]));
        }
    }

    if constexpr (MODE == 1) {
        const int mat   = n0 >> 10;       // 0=Q, 1=K, 2=V (block-uniform)
        const int bb    = m0 >> 10;
        const int tbase = m0 & 1023;
        if (mat < 2) {
            const float* bp = (mat == 0) ? biasQ : biasK;
            ushort* dst = (mat == 0) ? (ushort*)out : (ushort*)out2;
            float bvals[2][2];
#pragma unroll
            for (int nq = 0; nq < 2; ++nq)
#pragma unroll
                for (int ni = 0; ni < 2; ++ni)
                    bvals[nq][ni] =
                        bp[(n0 & 1023) + nq * 128 + wc * 32 + ni * 16 + (lane & 15)];
#pragma unroll
            for (int mq = 0; mq < 2; ++mq)
#pragma unroll
            for (int mi = 0; mi < 4; ++mi)
#pragma unroll
            for (int nq = 0; nq < 2; ++nq)
#pragma unroll
            for (int ni = 0; ni < 2; ++ni) {
                const int cn = (n0 & 1023) + nq * 128 + wc * 32 + ni * 16 + (lane & 15);
                const int h = cn >> 6, dd = cn & 63;
                const int t0 = tbase + mq * 128 + wr * 64 + mi * 16 + (lane >> 4) * 4;
#pragma unroll
                for (int r = 0; r < 4; ++r)
                    dst[((size_t)(bb * 16 + h) * 1024 + t0 + r) * 64 + dd] =
                        f2b(acc[mq][mi][nq][ni][r] + bvals[nq][ni]);
            }
        } else {
            // V: transpose 256(t) x 256(dim) through LDS, 128 dims at a time.
            const int vb = n0 - 2048;
            ushort* T = lds;              // [128][264] ushort (264 = pad)
            ushort* Vt = (ushort*)out3;
            const int dimL = wc * 32 + (lane & 15);
#pragma unroll 1
            for (int dh = 0; dh < 2; ++dh) {     // dh == nq
                __syncthreads();
#pragma unroll
                for (int ni = 0; ni < 2; ++ni) {
                    const float bv = biasV[vb + dh * 128 + dimL + ni * 16];
#pragma unroll
                    for (int mq = 0; mq < 2; ++mq)
#pragma unroll
                    for (int mi = 0; mi < 4; ++mi) {
                        const int t0 = mq * 128 + wr * 64 + mi * 16 + (lane >> 4) * 4;
#pragma unroll
                        for (int r = 0; r < 4; ++r)
                            T[(dimL + ni * 16) * 264 + t0 + r] =
                                f2b(acc[mq][mi][dh][ni][r] + bv);
                    }
                }
                __syncthreads();
#pragma unroll
                for (int it = 0; it < 8; ++it) {
                    const int idx = it * 512 + tid;
                    const int row = idx >> 5, ch = idx & 31;
                    const uint4 vv = *(const uint4*)&T[row * 264 + ch * 8];
                    const int d  = vb + dh * 128 + row;
                    const int hh = d >> 6, dl = d & 63;
                    *(uint4*)&Vt[((size_t)(bb * 16 + hh) * 64 + dl) * 1024 + tbase + ch * 8] = vv;
                }
            }
        }
    }
}

// ---------------------------------------------------------------------------
// 128x128 GEMM (MODE 2 only): fp32 out = resid + acc + bias. Wo / FFN2.
// ---------------------------------------------------------------------------
__global__ __launch_bounds__(256)
void gemm_res(const ushort* __restrict__ A, const ushort* __restrict__ Bt,
              const float* __restrict__ bias, float* __restrict__ out,
              const float* __restrict__ resid, int N, int K) {
    __shared__ ushort lds[128 * 64 * 2];
    ushort* sA = lds;
    ushort* sB = lds + 128 * 64;

    const int tid  = threadIdx.x;
    const int lane = tid & 63;
    const int wave = tid >> 6;
    const int l31  = lane & 31;
    const int half = lane >> 5;
    const int wm   = (wave & 1) * 64;
    const int wn   = (wave >> 1) * 64;
    const int m0   = blockIdx.y * 128;
    const int n0   = blockIdx.x * 128;

    floatx16 acc[2][2] = {};

    const int lrow = lane >> 3;
    const int scb  = (lane & 7) ^ lrow;
    const ushort* Ag = A  + (size_t)(m0 + wave * 8 + lrow) * K + scb * 8;
    const ushort* Bg = Bt + (size_t)(n0 + wave * 8 + lrow) * K + scb * 8;

    for (int k0 = 0; k0 < K; k0 += 64) {
        __syncthreads();
#pragma unroll
        for (int p = 0; p < 4; ++p) {
            gl_lds16(Ag + (size_t)(p * 32) * K + k0, sA + (p * 32 + wave * 8) * 64);
            gl_lds16(Bg + (size_t)(p * 32) * K + k0, sB + (p * 32 + wave * 8) * 64);
        }
        __syncthreads();
#pragma unroll
        for (int ks = 0; ks < 4; ++ks) {
            const int cx = ks * 2 + half;
            shortx8 af[2], bf[2];
#pragma unroll
            for (int i = 0; i < 2; ++i) {
                const int r = wm + i * 32 + l31;
                af[i] = *(const shortx8*)&sA[r * 64 + (cx ^ (r & 7)) * 8];
            }
#pragma unroll
            for (int j = 0; j < 2; ++j) {
                const int r = wn + j * 32 + l31;
                bf[j] = *(const shortx8*)&sB[r * 64 + (cx ^ (r & 7)) * 8];
            }
#pragma unroll
            for (int i = 0; i < 2; ++i)
#pragma unroll
                for (int j = 0; j < 2; ++j)
                    acc[i][j] = __builtin_amdgcn_mfma_f32_32x32x16_bf16(
                        af[i], bf[j], acc[i][j], 0, 0, 0);
        }
    }
#pragma unroll
    for (int i = 0; i < 2; ++i)
#pragma unroll
        for (int j = 0; j < 2; ++j) {
            const int gn = n0 + wn + j * 32 + l31;
            const float bv = bias[gn];
#pragma unroll
            for (int reg = 0; reg < 16; ++reg) {
                const int gm = m0 + wm + i * 32 + (reg & 3) + 8 * (reg >> 2) + 4 * half;
                out[(size_t)gm * N + gn] =
                    acc[i][j][reg] + bv + resid[(size_t)gm * N + gn];
            }
        }
}

// ---------------------------------------------------------------------------
// Flash-style causal attention, LDS-staged (unchanged).
// ---------------------------------------------------------------------------
__global__ __launch_bounds__(256)
void attn_kernel(const ushort* __restrict__ Q, const ushort* __restrict__ Kk,
                 const ushort* __restrict__ Vt, ushort* __restrict__ ctx) {
    __shared__ ushort sK[64 * 64];
    __shared__ ushort sV[64 * 64];     // V^T tile: [d][64 kv-cols]
    __shared__ ushort sP[4][16 * 72];

    const int tid  = threadIdx.x;
    const int lane = tid & 63;
    const int wave = tid >> 6;
    const int quad = lane >> 4;
    const int l15  = lane & 15;

    const int qb = 15 - (blockIdx.x >> 7);   // descending workload
    const int bh = blockIdx.x & 127;
    const size_t base = (size_t)bh << 16;    // bh*1024*64
    const int bb = bh >> 4, h = bh & 15;

    const int lrow = lane >> 3;
    const int scb  = (lane & 7) ^ lrow;
    const ushort* Kg = Kk + base + (size_t)(wave * 8 + lrow) * 64 + scb * 8;
    const ushort* Vg = Vt + base + (size_t)(wave * 8 + lrow) * 1024 + scb * 8;

    const int qrow = qb * 64 + wave * 16 + l15;
    const shortx8 qf0 = *(const shortx8*)&Q[base + (size_t)qrow * 64 + quad * 8];
    const shortx8 qf1 = *(const shortx8*)&Q[base + (size_t)qrow * 64 + 32 + quad * 8];

    const float SC = 0.125f * 1.44269504f;   // exp2-domain scaling

    float mstate[4], lstate[4];
    floatx4 oacc[4] = {};
#pragma unroll
    for (int r = 0; r < 4; ++r) { mstate[r] = -__builtin_inff(); lstate[r] = 0.0f; }

    for (int kt = 0; kt <= qb; ++kt) {
        __syncthreads();
#pragma unroll
        for (int p = 0; p < 2; ++p) {
            gl_lds16(Kg + (size_t)kt * 4096 + (size_t)p * 2048,
                     sK + (p * 32 + wave * 8) * 64);
            gl_lds16(Vg + (size_t)kt * 64 + (size_t)p * 32 * 1024,
                     sV + (p * 32 + wave * 8) * 64);
        }
        __syncthreads();

        floatx4 s[4];
#pragma unroll
        for (int nt = 0; nt < 4; ++nt) {
            const int r = nt * 16 + l15;
            const int c0 = quad ^ (r & 7);
            const int c1 = (4 + quad) ^ (r & 7);
            const shortx8 kf0 = *(const shortx8*)&sK[r * 64 + c0 * 8];
            const shortx8 kf1 = *(const shortx8*)&sK[r * 64 + c1 * 8];
            floatx4 z = {};
            z = __builtin_amdgcn_mfma_f32_16x16x32_bf16(qf0, kf0, z, 0, 0, 0);
            z = __builtin_amdgcn_mfma_f32_16x16x32_bf16(qf1, kf1, z, 0, 0, 0);
            s[nt] = z;
        }
#pragma unroll
        for (int nt = 0; nt < 4; ++nt)
#pragma unroll
            for (int r = 0; r < 4; ++r) {
                float sv = s[nt][r] * SC;
                if (kt == qb) {
                    const int col = nt * 16 + l15;
                    const int row = wave * 16 + quad * 4 + r;
                    if (col > row) sv = -__builtin_inff();
                }
                s[nt][r] = sv;
            }
        float mnew[4], alpha[4];
#pragma unroll
        for (int r = 0; r < 4; ++r) {
            float mt = fmaxf(fmaxf(s[0][r], s[1][r]), fmaxf(s[2][r], s[3][r]));
#pragma unroll
            for (int o = 8; o >= 1; o >>= 1) mt = fmaxf(mt, __shfl_xor(mt, o, 64));
            mnew[r]  = fmaxf(mstate[r], mt);
            alpha[r] = exp2f(mstate[r] - mnew[r]);
            mstate[r] = mnew[r];
        }
#pragma unroll
        for (int r = 0; r < 4; ++r) {
            float rs = 0.0f;
#pragma unroll
            for (int nt = 0; nt < 4; ++nt) {
                const float p = exp2f(s[nt][r] - mnew[r]);
                s[nt][r] = p;
                rs += p;
            }
#pragma unroll
            for (int o = 8; o >= 1; o >>= 1) rs += __shfl_xor(rs, o, 64);
            lstate[r] = alpha[r] * lstate[r] + rs;
#pragma unroll
            for (int dt = 0; dt < 4; ++dt) oacc[dt][r] *= alpha[r];
        }
#pragma unroll
        for (int nt = 0; nt < 4; ++nt)
#pragma unroll
            for (int r = 0; r < 4; ++r)
                sP[wave][(quad * 4 + r) * 72 + nt * 16 + l15] = f2b(s[nt][r]);
        __asm__ volatile("s_waitcnt lgkmcnt(0)" ::: "memory");
        const shortx8 pf0 = *(const shortx8*)&sP[wave][l15 * 72 + quad * 8];
        const shortx8 pf1 = *(const shortx8*)&sP[wave][l15 * 72 + 32 + quad * 8];
#pragma unroll
        for (int dt = 0; dt < 4; ++dt) {
            const int r = dt * 16 + l15;
            const int c0 = quad ^ (r & 7);
            const int c1 = (4 + quad) ^ (r & 7);
            const shortx8 v0 = *(const shortx8*)&sV[r * 64 + c0 * 8];
            const shortx8 v1 = *(const shortx8*)&sV[r * 64 + c1 * 8];
            oacc[dt] = __builtin_amdgcn_mfma_f32_16x16x32_bf16(pf0, v0, oacc[dt], 0, 0, 0);
            oacc[dt] = __builtin_amdgcn_mfma_f32_16x16x32_bf16(pf1, v1, oacc[dt], 0, 0, 0);
        }
    }
#pragma unroll
    for (int dt = 0; dt < 4; ++dt)
#pragma unroll
        for (int r = 0; r < 4; ++r) {
            const int t = qb * 64 + wave * 16 + quad * 4 + r;
            const int dim = dt * 16 + l15;
            const float v = oacc[dt][r] / lstate[r];
            ctx[(size_t)(bb * 1024 + t) * 1024 + h * 64 + dim] = f2b(v);
        }
}

// ---------------------------------------------------------------------------
// Launch
// ---------------------------------------------------------------------------
extern "C" void kernel_launch(void* const* d_in, const int* in_sizes, int n_in,
                              void* d_out, int out_size, void* d_ws, size_t ws_size,
                              hipStream_t stream) {
    const float* x    = (const float*)d_in[0];
    const float* ln1w = (const float*)d_in[2];
    const float* ln1b = (const float*)d_in[3];
    const float* ln2w = (const float*)d_in[4];
    const float* ln2b = (const float*)d_in[5];
    const float* wq   = (const float*)d_in[6];
    const float* bq   = (const float*)d_in[7];
    const float* wk   = (const float*)d_in[8];
    const float* bk   = (const float*)d_in[9];
    const float* wv   = (const float*)d_in[10];
    const float* bv   = (const float*)d_in[11];
    const float* wo   = (const float*)d_in[12];
    const float* bo   = (const float*)d_in[13];
    const float* w1   = (const float*)d_in[14];
    const float* b1   = (const float*)d_in[15];
    const float* w2   = (const float*)d_in[16];
    const float* b2   = (const float*)d_in[17];

    char* ws = (char*)d_ws;
    const size_t MB = 1024 * 1024;
    ushort* WQKVT = (ushort*)(ws + 0 * MB);     // [3072][1024] bf16 (wq|wk|wv ^T)
    ushort* WOT   = (ushort*)(ws + 6 * MB);     // [1024][1024]
    ushort* W1T   = (ushort*)(ws + 8 * MB);     // [4096][1024]
    ushort* W2T   = (ushort*)(ws + 16 * MB);    // [1024][4096]
    ushort* H1    = (ushort*)(ws + 24 * MB);    // [8192][1024]; H2 overlays later
    ushort* H2    = H1;
    ushort* Qb    = (ushort*)(ws + 40 * MB);    // [128][1024][64]
    ushort* Kb    = (ushort*)(ws + 56 * MB);    // [128][1024][64]
    ushort* Vbt   = (ushort*)(ws + 72 * MB);    // [128][64][1024]
    ushort* FF1   = (ushort*)(ws + 40 * MB);    // [8192][4096] overlays Q,K,V (dead)
    ushort* CTX   = (ushort*)(ws + 104 * MB);   // [8192][1024]

    float* xout = (float*)d_out;                // x2 lives here, then final out

    const dim3 tb(32, 8);
    transp4_kernel<<<dim3(32, 32, 4), tb, 0, stream>>>(
        wq, wk, wv, wo,
        WQKVT, WQKVT + 1024 * 1024, WQKVT + 2048 * 1024, WOT);
    transp_kernel<<<dim3(128, 32), tb, 0, stream>>>(w1, W1T, 1024, 4096);
    transp_kernel<<<dim3(32, 128), tb, 0, stream>>>(w2, W2T, 4096, 1024);

    ln_kernel<<<8192, 256, 0, stream>>>(x, ln1w, ln1b, H1);

    gemm8<1><<<dim3(12, 32), 512, 0, stream>>>(H1, WQKVT, bq, bk, bv,
                                               Qb, Kb, Vbt, 3072, 1024);

    attn_kernel<<<2048, 256, 0, stream>>>(Qb, Kb, Vbt, CTX);

    gemm_res<<<dim3(8, 64), 256, 0, stream>>>(CTX, WOT, bo, xout, x, 1024, 1024);

    ln_kernel<<<8192, 256, 0, stream>>>(xout, ln2w, ln2b, H2);

    gemm8<3><<<dim3(16, 32), 512, 0, stream>>>(H2, W1T, b1, nullptr, nullptr,
                                               FF1, nullptr, nullptr, 4096, 1024);

    gemm_res<<<dim3(8, 64), 256, 0, stream>>>(FF1, W2T, b2, xout, xout, 1024, 4096);

    (void)in_sizes; (void)n_in; (void)out_size; (void)ws_size;
}

// Round 2
// 483.225 us; speedup vs baseline: 1.1845x; 1.1845x over previous
//
#include <hip/hip_runtime.h>
#include <hip/hip_bf16.h>
#include <math.h>

// ---------------------------------------------------------------------------
// TransformerBlock: B=8 T=1024 C=1024 H=16 d=64, bf16 MFMA compute, fp32 acc.
// R7: keep R6's 8-phase 256x256 pipelined K-loop (verified correct), but
//  (a) LDS-restage ALL epilogues -> full-cacheline HBM writes (R6 wrote 32B
//      partials: WRITE_SIZE 245MB vs 64MB logical),
//  (b) replace gemm_res with gemm8r: 256x128-tile 2-phase counted-vmcnt
//      pipeline + XCD-chunked swizzle + coalesced fp32/resid epilogue.
// ---------------------------------------------------------------------------

#define DEVI __device__ __forceinline__

typedef __attribute__((ext_vector_type(4))) float floatx4;
typedef __attribute__((ext_vector_type(16))) float floatx16;
typedef __attribute__((ext_vector_type(8))) short shortx8;   // 8 bf16 = 4 VGPRs

DEVI ushort f2b(float f) {
    __hip_bfloat16 h = __float2bfloat16(f);
    return __builtin_bit_cast(ushort, h);
}

DEVI void gl_lds16(const ushort* g, ushort* l) {
    // 16B direct global->LDS. LDS dest = wave-uniform base + lane*16.
    __builtin_amdgcn_global_load_lds(
        (const __attribute__((address_space(1))) void*)g,
        (__attribute__((address_space(3))) void*)l, 16, 0, 0);
}

// tanh-form GeLU: |err| vs erf-GeLU ~3e-3 — far under the bf16 threshold.
DEVI float gelu_f(float v) {
    const float u0 = 0.7978845608f * v * (1.0f + 0.044715f * v * v);
    const float u  = fminf(fmaxf(u0, -15.0f), 15.0f);
    const float e  = exp2f(u * 2.885390082f);      // e^{2u}
    const float th = 1.0f - 2.0f / (e + 1.0f);     // tanh(u)
    return 0.5f * v * (1.0f + th);
}

// ---------------------------------------------------------------------------
// Fused transpose of the four 1024x1024 weights (z picks the matrix).
// ---------------------------------------------------------------------------
__global__ void transp4_kernel(const float* __restrict__ s0, const float* __restrict__ s1,
                               const float* __restrict__ s2, const float* __restrict__ s3,
                               ushort* __restrict__ d0, ushort* __restrict__ d1,
                               ushort* __restrict__ d2, ushort* __restrict__ d3) {
    const int z = blockIdx.z;
    const float* src = (z == 0) ? s0 : (z == 1) ? s1 : (z == 2) ? s2 : s3;
    ushort*      dst = (z == 0) ? d0 : (z == 1) ? d1 : (z == 2) ? d2 : d3;
    __shared__ float tile[32][33];
    const int c0 = blockIdx.x * 32, r0 = blockIdx.y * 32;
    const int tx = threadIdx.x, ty = threadIdx.y;   // 32 x 8
#pragma unroll
    for (int i = 0; i < 32; i += 8)
        tile[ty + i][tx] = src[(size_t)(r0 + ty + i) * 1024 + c0 + tx];
    __syncthreads();
#pragma unroll
    for (int i = 0; i < 32; i += 8)
        dst[(size_t)(c0 + ty + i) * 1024 + r0 + tx] = f2b(tile[tx][ty + i]);
}

__global__ void transp_kernel(const float* __restrict__ src,
                              ushort* __restrict__ dst, int R, int C) {
    __shared__ float tile[32][33];
    const int c0 = blockIdx.x * 32, r0 = blockIdx.y * 32;
    const int tx = threadIdx.x, ty = threadIdx.y;   // 32 x 8
#pragma unroll
    for (int i = 0; i < 32; i += 8)
        tile[ty + i][tx] = src[(size_t)(r0 + ty + i) * C + c0 + tx];
    __syncthreads();
#pragma unroll
    for (int i = 0; i < 32; i += 8)
        dst[(size_t)(c0 + ty + i) * R + r0 + tx] = f2b(tile[tx][ty + i]);
}

// ---------------------------------------------------------------------------
// LayerNorm over C=1024, one block (256 thr) per token. fp32 in, bf16 out.
// ---------------------------------------------------------------------------
__global__ __launch_bounds__(256)
void ln_kernel(const float* __restrict__ x, const float* __restrict__ w,
               const float* __restrict__ b, ushort* __restrict__ out) {
    __shared__ float red[8];
    const int m = blockIdx.x;
    const int tid = threadIdx.x;
    const float4 xv = *(const float4*)&x[(size_t)m * 1024 + tid * 4];
    float s  = xv.x + xv.y + xv.z + xv.w;
    float s2 = xv.x * xv.x + xv.y * xv.y + xv.z * xv.z + xv.w * xv.w;
#pragma unroll
    for (int o = 32; o >= 1; o >>= 1) {
        s  += __shfl_xor(s, o, 64);
        s2 += __shfl_xor(s2, o, 64);
    }
    const int wv_ = tid >> 6;
    if ((tid & 63) == 0) { red[wv_] = s; red[4 + wv_] = s2; }
    __syncthreads();
    s  = red[0] + red[1] + red[2] + red[3];
    s2 = red[4] + red[5] + red[6] + red[7];
    const float mu   = s * (1.0f / 1024.0f);
    const float var  = s2 * (1.0f / 1024.0f) - mu * mu;
    const float rstd = rsqrtf(var + 1e-5f);
    const float4 wv = *(const float4*)&w[tid * 4];
    const float4 bv = *(const float4*)&b[tid * 4];
    ushort o4[4];
    o4[0] = f2b((xv.x - mu) * rstd * wv.x + bv.x);
    o4[1] = f2b((xv.y - mu) * rstd * wv.y + bv.y);
    o4[2] = f2b((xv.z - mu) * rstd * wv.z + bv.z);
    o4[3] = f2b((xv.w - mu) * rstd * wv.w + bv.w);
    *(uint2*)&out[(size_t)m * 1024 + tid * 4] = *(uint2*)o4;
}

// ---------------------------------------------------------------------------
// Shared pieces of the pipelined GEMMs.
// ---------------------------------------------------------------------------

#define STAGE_A(j, h) { const int c_ = (j) & 1;                                         \
    gl_lds16(pA + (size_t)((h) * 128) * K + (j) * 64,                                   \
             lds + c_ * 16384 + (h) * 8192 + dOff);                                     \
    gl_lds16(pA + (size_t)((h) * 128 + 8) * K + (j) * 64,                               \
             lds + c_ * 16384 + (h) * 8192 + dOff + 512); }

#define STAGE_B(j, h) { const int c_ = (j) & 1;                                         \
    gl_lds16(pB + (size_t)((h) * 128) * K + (j) * 64,                                   \
             lds + 32768 + c_ * 16384 + (h) * 8192 + dOff);                             \
    gl_lds16(pB + (size_t)((h) * 128 + 8) * K + (j) * 64,                               \
             lds + 32768 + c_ * 16384 + (h) * 8192 + dOff + 512); }

#define LOAD_A(mq, c) { const ushort* ap = lds + (c) * 16384 + (mq) * 8192;             \
    _Pragma("unroll") for (int mi = 0; mi < 4; ++mi) {                                  \
        af[mi][0] = *(const shortx8*)&ap[aBase + mi * 1024];                            \
        af[mi][1] = *(const shortx8*)&ap[(aBase ^ 32) + mi * 1024]; } }

#define LOAD_B(nq, c) { const ushort* bp = lds + 32768 + (c) * 16384 + (nq) * 8192;     \
    _Pragma("unroll") for (int ni = 0; ni < 2; ++ni) {                                  \
        bf[ni][0] = *(const shortx8*)&bp[bBase + ni * 1024];                            \
        bf[ni][1] = *(const shortx8*)&bp[(bBase ^ 32) + ni * 1024]; } }

#define MFMA16(mq, nq) {                                                                \
    _Pragma("unroll") for (int mi = 0; mi < 4; ++mi)                                    \
    _Pragma("unroll") for (int ni = 0; ni < 2; ++ni)                                    \
    _Pragma("unroll") for (int ks = 0; ks < 2; ++ks)                                    \
        acc[mq][mi][nq][ni] = __builtin_amdgcn_mfma_f32_16x16x32_bf16(                  \
            af[mi][ks], bf[ni][ks], acc[mq][mi][nq][ni], 0, 0, 0); }

#define PH_SYNC() { __builtin_amdgcn_s_barrier();                                       \
    asm volatile("s_waitcnt lgkmcnt(0)" ::: "memory");                                  \
    __builtin_amdgcn_sched_barrier(0); }

// ---------------------------------------------------------------------------
// 256x256 8-phase pipelined GEMM (T2+T3+T4+T5). 512 thr = 8 waves (2M x 4N),
// BK=64, double-buffered 128KB LDS, mfma_f32_16x16x32_bf16.
//   MODE 1: fused QKV (Q/K head layouts; V^T via LDS transpose)
//   MODE 3: bf16 out = gelu(acc + bias)
// All epilogues restage C through LDS -> 512B-contiguous full-line stores.
// ---------------------------------------------------------------------------
template <int MODE>
__global__ __launch_bounds__(512, 2)
void gemm8(const ushort* __restrict__ A, const ushort* __restrict__ Bt,
           const float* __restrict__ biasQ, const float* __restrict__ biasK,
           const float* __restrict__ biasV,
           void* __restrict__ out, void* __restrict__ out2, void* __restrict__ out3,
           int N, int K) {
    __shared__ __align__(16) ushort lds[65536];   // 128 KB: sA[2][256x64] | sB[2][256x64]

    const int tid  = threadIdx.x;
    const int lane = tid & 63;
    const int w    = tid >> 6;       // 0..7
    const int wr   = w >> 2;         // 0..1  (M sub-tile)
    const int wc   = w & 3;          // 0..3  (N sub-tile)

    // XCD-aware bijective block swizzle (nwg % 8 == 0 for all our grids)
    int bx = blockIdx.x, by = blockIdx.y;
    {
        const int nwg = gridDim.x * gridDim.y;
        if ((nwg & 7) == 0) {
            const int flat = by * gridDim.x + bx;
            const int cpx  = nwg >> 3;
            const int wg   = (flat & 7) * cpx + (flat >> 3);
            bx = wg % gridDim.x;
            by = wg / gridDim.x;
        }
    }
    const int m0 = by * 256;
    const int n0 = bx * 256;
    const int NT = K >> 6;           // K-tiles of 64 (K=1024 -> 16)

    floatx4 acc[2][4][2][2] = {};    // [mq][mi][nq][ni]

    // ---- staging addresses (global source pre-swizzled, LDS dest linear) ----
    const int lr3 = lane >> 3;            // 0..7
    const int sc  = (lane & 7) ^ lr3;     // swizzled source col-block
    const ushort* pA = A  + (size_t)(m0 + w * 16 + lr3) * K + sc * 8;
    const ushort* pB = Bt + (size_t)(n0 + w * 16 + lr3) * K + sc * 8;
    const int dOff = w * 1024;            // ushort units; +512 for 2nd issue

    // ---- fragment read addresses (swizzled on read; r&7 == lane&7) ----
    const int c0    = (lane >> 4) ^ (lane & 7);
    const int aBase = (wr * 64 + (lane & 15)) * 64 + c0 * 8;
    const int bBase = (wc * 32 + (lane & 15)) * 64 + c0 * 8;

    shortx8 af[4][2], bf[2][2];

    // ---- prologue: tile 0 fully + A0/B1 of tile 1 (12 loads/thread) ----
    STAGE_A(0, 0); STAGE_B(0, 1); STAGE_A(0, 1); STAGE_B(0, 0);
    STAGE_A(1, 0); STAGE_B(1, 1);

#pragma unroll 1
    for (int j = 0; j < NT; ++j) {
        const int c = j & 1;
        // K-tile gate: everything except the last 2 half-tiles has landed.
        if (j == NT - 1) { asm volatile("s_waitcnt vmcnt(0)" ::: "memory"); }
        else             { asm volatile("s_waitcnt vmcnt(4)" ::: "memory"); }
        __builtin_amdgcn_s_barrier();

        // p0: (mq0, nq0) — reads A0,B0; stages A1(j+1) into other buffer
        LOAD_A(0, c); LOAD_B(0, c);
        if (j + 1 < NT) STAGE_A(j + 1, 1);
        PH_SYNC();
        __builtin_amdgcn_s_setprio(1); MFMA16(0, 0); __builtin_amdgcn_s_setprio(0);
        __builtin_amdgcn_s_barrier();

        // p1: (mq0, nq1) — reads A0,B1; stages B0(j+1)
        LOAD_B(1, c);
        if (j + 1 < NT) STAGE_B(j + 1, 0);
        PH_SYNC();
        __builtin_amdgcn_s_setprio(1); MFMA16(0, 1); __builtin_amdgcn_s_setprio(0);
        __builtin_amdgcn_s_barrier();

        // p2: (mq1, nq1) — reads A1,B1; stages A0(j+2) over dead A0 (this buf)
        LOAD_A(1, c);
        if (j + 2 < NT) STAGE_A(j + 2, 0);
        PH_SYNC();
        __builtin_amdgcn_s_setprio(1); MFMA16(1, 1); __builtin_amdgcn_s_setprio(0);
        __builtin_amdgcn_s_barrier();

        // p3: (mq1, nq0) — reads A1,B0; stages B1(j+2) over dead B1 (this buf)
        LOAD_B(0, c);
        if (j + 2 < NT) STAGE_B(j + 2, 1);
        PH_SYNC();
        __builtin_amdgcn_s_setprio(1); MFMA16(1, 0); __builtin_amdgcn_s_setprio(0);
        // no barrier here: the loop-head gate (vmcnt + barrier) closes the tile
    }

    // ---- epilogue. C/D map (16x16x32): row=(lane>>4)*4+reg, col=lane&15.
    //      All paths restage through LDS T[128][264] and store 16B/lane rows.
    const int colL  = wc * 32 + (lane & 15);          // + nq*128 + ni*16
    const int rbase = wr * 64 + ((lane >> 4) << 2);   // + mi*16 + r (local to half)

    if constexpr (MODE == 3) {
        float bvals[2][2];
#pragma unroll
        for (int nq = 0; nq < 2; ++nq)
#pragma unroll
            for (int ni = 0; ni < 2; ++ni)
                bvals[nq][ni] = biasQ[n0 + nq * 128 + colL + ni * 16];
        ushort* o = (ushort*)out;
        ushort* T = lds;                  // [128][264]
#pragma unroll
        for (int mq = 0; mq < 2; ++mq) {
            __syncthreads();
#pragma unroll
            for (int mi = 0; mi < 4; ++mi)
#pragma unroll
            for (int nq = 0; nq < 2; ++nq)
#pragma unroll
            for (int ni = 0; ni < 2; ++ni) {
                const int cc = nq * 128 + colL + ni * 16;
                const int t0 = rbase + mi * 16;
#pragma unroll
                for (int r = 0; r < 4; ++r)
                    T[(t0 + r) * 264 + cc] =
                        f2b(gelu_f(acc[mq][mi][nq][ni][r] + bvals[nq][ni]));
            }
            __syncthreads();
#pragma unroll
            for (int it = 0; it < 8; ++it) {
                const int idx = it * 512 + tid;
                const int row = idx >> 5, ch = idx & 31;
                const uint4 vv = *(const uint4*)&T[row * 264 + ch * 8];
                *(uint4*)&o[(size_t)(m0 + mq * 128 + row) * N + n0 + ch * 8] = vv;
            }
        }
    }

    if constexpr (MODE == 1) {
        const int mat   = n0 >> 10;       // 0=Q, 1=K, 2=V (block-uniform)
        const int bb    = m0 >> 10;
        const int tbase = m0 & 1023;
        if (mat < 2) {
            const float* bp = (mat == 0) ? biasQ : biasK;
            ushort* dst = (mat == 0) ? (ushort*)out : (ushort*)out2;
            float bvals[2][2];
#pragma unroll
            for (int nq = 0; nq < 2; ++nq)
#pragma unroll
                for (int ni = 0; ni < 2; ++ni)
                    bvals[nq][ni] = bp[(n0 & 1023) + nq * 128 + colL + ni * 16];
            ushort* T = lds;              // [128][264]
#pragma unroll
            for (int mq = 0; mq < 2; ++mq) {
                __syncthreads();
#pragma unroll
                for (int mi = 0; mi < 4; ++mi)
#pragma unroll
                for (int nq = 0; nq < 2; ++nq)
#pragma unroll
                for (int ni = 0; ni < 2; ++ni) {
                    const int cc = nq * 128 + colL + ni * 16;
                    const int t0 = rbase + mi * 16;
#pragma unroll
                    for (int r = 0; r < 4; ++r)
                        T[(t0 + r) * 264 + cc] =
                            f2b(acc[mq][mi][nq][ni][r] + bvals[nq][ni]);
                }
                __syncthreads();
#pragma unroll
                for (int it = 0; it < 8; ++it) {
                    const int idx = it * 512 + tid;
                    const int row = idx >> 5, ch = idx & 31;
                    const uint4 vv = *(const uint4*)&T[row * 264 + ch * 8];
                    const int cg = (n0 & 1023) + ch * 8;     // 8 ushorts, one head
                    const int h = cg >> 6, dd = cg & 63;
                    const int t = tbase + mq * 128 + row;
                    *(uint4*)&dst[((size_t)(bb * 16 + h) * 1024 + t) * 64 + dd] = vv;
                }
            }
        } else {
            // V: transpose 256(t) x 256(dim) through LDS, 128 dims at a time.
            const int vb = n0 - 2048;
            ushort* T = lds;              // [128][264]
            ushort* Vt = (ushort*)out3;
            const int dimL = wc * 32 + (lane & 15);
#pragma unroll
            for (int dh = 0; dh < 2; ++dh) {     // dh == nq (static index!)
                __syncthreads();
#pragma unroll
                for (int ni = 0; ni < 2; ++ni) {
                    const float bv = biasV[vb + dh * 128 + dimL + ni * 16];
#pragma unroll
                    for (int mq = 0; mq < 2; ++mq)
#pragma unroll
                    for (int mi = 0; mi < 4; ++mi) {
                        const int t0 = mq * 128 + wr * 64 + mi * 16 + (lane >> 4) * 4;
#pragma unroll
                        for (int r = 0; r < 4; ++r)
                            T[(dimL + ni * 16) * 264 + t0 + r] =
                                f2b(acc[mq][mi][dh][ni][r] + bv);
                    }
                }
                __syncthreads();
#pragma unroll
                for (int it = 0; it < 8; ++it) {
                    const int idx = it * 512 + tid;
                    const int row = idx >> 5, ch = idx & 31;
                    const uint4 vv = *(const uint4*)&T[row * 264 + ch * 8];
                    const int d  = vb + dh * 128 + row;
                    const int hh = d >> 6, dl = d & 63;
                    *(uint4*)&Vt[((size_t)(bb * 16 + hh) * 64 + dl) * 1024 + tbase + ch * 8] = vv;
                }
            }
        }
    }
}

// ---------------------------------------------------------------------------
// gemm8r: 256(M) x 128(N) tile, 2-phase-per-K-tile counted-vmcnt pipeline.
// fp32 out = acc + bias + resid, coalesced via LDS restage. Wo / FFN2.
// LDS 96KB: sA[2][256x64] (64KB) | sB[2][128x64] (32KB).
// Stage schedule: p0 stages A1(j+1)+B(j+1); p1 stages A0(j+2).
// Gate: vmcnt(2) per K-tile (A0(j+1) may remain in flight).
// ---------------------------------------------------------------------------

#define STAGE_BR(j) { const int c_ = (j) & 1;                                           \
    gl_lds16(pB + (size_t)0 * K + (j) * 64, lds + 32768 + c_ * 8192 + dOff);            \
    gl_lds16(pB + (size_t)8 * K + (j) * 64, lds + 32768 + c_ * 8192 + dOff + 512); }

#define LOAD_BR(c) { const ushort* bp = lds + 32768 + (c) * 8192;                       \
    _Pragma("unroll") for (int ni = 0; ni < 2; ++ni) {                                  \
        bf[ni][0] = *(const shortx8*)&bp[bBase + ni * 1024];                            \
        bf[ni][1] = *(const shortx8*)&bp[(bBase ^ 32) + ni * 1024]; } }

#define MFMA16R(mq) {                                                                   \
    _Pragma("unroll") for (int mi = 0; mi < 4; ++mi)                                    \
    _Pragma("unroll") for (int ni = 0; ni < 2; ++ni)                                    \
    _Pragma("unroll") for (int ks = 0; ks < 2; ++ks)                                    \
        acc[mq][mi][ni] = __builtin_amdgcn_mfma_f32_16x16x32_bf16(                      \
            af[mi][ks], bf[ni][ks], acc[mq][mi][ni], 0, 0, 0); }

__global__ __launch_bounds__(512, 2)
void gemm8r(const ushort* __restrict__ A, const ushort* __restrict__ Bt,
            const float* __restrict__ bias, float* __restrict__ out,
            const float* __restrict__ resid, int N, int K) {
    __shared__ __align__(16) ushort lds[49152];   // 96 KB

    const int tid  = threadIdx.x;
    const int lane = tid & 63;
    const int w    = tid >> 6;
    const int wr   = w >> 2;         // 0..1
    const int wc   = w & 3;          // 0..3

    int bx = blockIdx.x, by = blockIdx.y;
    {
        const int nwg = gridDim.x * gridDim.y;
        if ((nwg & 7) == 0) {
            const int flat = by * gridDim.x + bx;
            const int cpx  = nwg >> 3;
            const int wg   = (flat & 7) * cpx + (flat >> 3);
            bx = wg % gridDim.x;
            by = wg / gridDim.x;
        }
    }
    const int m0 = by * 256;
    const int n0 = bx * 128;
    const int NT = K >> 6;

    floatx4 acc[2][4][2] = {};       // [mq][mi][ni]

    const int lr3 = lane >> 3;
    const int sc  = (lane & 7) ^ lr3;
    const ushort* pA = A  + (size_t)(m0 + w * 16 + lr3) * K + sc * 8;
    const ushort* pB = Bt + (size_t)(n0 + w * 16 + lr3) * K + sc * 8;
    const int dOff = w * 1024;

    const int c0    = (lane >> 4) ^ (lane & 7);
    const int aBase = (wr * 64 + (lane & 15)) * 64 + c0 * 8;
    const int bBase = (wc * 32 + (lane & 15)) * 64 + c0 * 8;

    shortx8 af[4][2], bf[2][2];

    // prologue: tile 0 fully + A0 of tile 1 (8 loads/thread)
    STAGE_A(0, 0); STAGE_A(0, 1); STAGE_BR(0); STAGE_A(1, 0);

#pragma unroll 1
    for (int j = 0; j < NT; ++j) {
        const int c = j & 1;
        if (j == NT - 1) { asm volatile("s_waitcnt vmcnt(0)" ::: "memory"); }
        else             { asm volatile("s_waitcnt vmcnt(2)" ::: "memory"); }
        __builtin_amdgcn_s_barrier();

        // p0: reads A0 + B (full, kept in regs across both phases);
        //     stages A1(j+1) and B(j+1) into other buffer (dead).
        LOAD_A(0, c); LOAD_BR(c);
        if (j + 1 < NT) { STAGE_A(j + 1, 1); STAGE_BR(j + 1); }
        PH_SYNC();
        __builtin_amdgcn_s_setprio(1); MFMA16R(0); __builtin_amdgcn_s_setprio(0);
        __builtin_amdgcn_s_barrier();

        // p1: reads A1; stages A0(j+2) over dead A0 (this buffer).
        LOAD_A(1, c);
        if (j + 2 < NT) STAGE_A(j + 2, 0);
        PH_SYNC();
        __builtin_amdgcn_s_setprio(1); MFMA16R(1); __builtin_amdgcn_s_setprio(0);
        // loop-head gate closes the tile
    }

    // epilogue: fp32 out = acc + bias + resid, restaged via T[128][132] fp32.
    float bvals[2];
#pragma unroll
    for (int ni = 0; ni < 2; ++ni)
        bvals[ni] = bias[n0 + wc * 32 + ni * 16 + (lane & 15)];
    float* T = (float*)lds;
    const int colL  = wc * 32 + (lane & 15);
    const int rbase = wr * 64 + ((lane >> 4) << 2);
#pragma unroll
    for (int mq = 0; mq < 2; ++mq) {
        __syncthreads();
#pragma unroll
        for (int mi = 0; mi < 4; ++mi)
#pragma unroll
        for (int ni = 0; ni < 2; ++ni) {
            const int t0 = rbase + mi * 16;
#pragma unroll
            for (int r = 0; r < 4; ++r)
                T[(t0 + r) * 132 + colL + ni * 16] = acc[mq][mi][ni][r] + bvals[ni];
        }
        __syncthreads();
#pragma unroll
        for (int it = 0; it < 8; ++it) {
            const int idx = it * 512 + tid;
            const int row = idx >> 5, ch = idx & 31;
            float4 tv = *(const float4*)&T[row * 132 + ch * 4];
            const size_t go = (size_t)(m0 + mq * 128 + row) * N + n0 + ch * 4;
            const float4 rv = *(const float4*)&resid[go];
            tv.x += rv.x; tv.y += rv.y; tv.z += rv.z; tv.w += rv.w;
            *(float4*)&out[go] = tv;
        }
    }
}

// ---------------------------------------------------------------------------
// Flash-style causal attention, LDS-staged (unchanged).
// ---------------------------------------------------------------------------
__global__ __launch_bounds__(256)
void attn_kernel(const ushort* __restrict__ Q, const ushort* __restrict__ Kk,
                 const ushort* __restrict__ Vt, ushort* __restrict__ ctx) {
    __shared__ ushort sK[64 * 64];
    __shared__ ushort sV[64 * 64];     // V^T tile: [d][64 kv-cols]
    __shared__ ushort sP[4][16 * 72];

    const int tid  = threadIdx.x;
    const int lane = tid & 63;
    const int wave = tid >> 6;
    const int quad = lane >> 4;
    const int l15  = lane & 15;

    const int qb = 15 - (blockIdx.x >> 7);   // descending workload
    const int bh = blockIdx.x & 127;
    const size_t base = (size_t)bh << 16;    // bh*1024*64
    const int bb = bh >> 4, h = bh & 15;

    const int lrow = lane >> 3;
    const int scb  = (lane & 7) ^ lrow;
    const ushort* Kg = Kk + base + (size_t)(wave * 8 + lrow) * 64 + scb * 8;
    const ushort* Vg = Vt + base + (size_t)(wave * 8 + lrow) * 1024 + scb * 8;

    const int qrow = qb * 64 + wave * 16 + l15;
    const shortx8 qf0 = *(const shortx8*)&Q[base + (size_t)qrow * 64 + quad * 8];
    const shortx8 qf1 = *(const shortx8*)&Q[base + (size_t)qrow * 64 + 32 + quad * 8];

    const float SC = 0.125f * 1.44269504f;   // exp2-domain scaling

    float mstate[4], lstate[4];
    floatx4 oacc[4] = {};
#pragma unroll
    for (int r = 0; r < 4; ++r) { mstate[r] = -__builtin_inff(); lstate[r] = 0.0f; }

    for (int kt = 0; kt <= qb; ++kt) {
        __syncthreads();
#pragma unroll
        for (int p = 0; p < 2; ++p) {
            gl_lds16(Kg + (size_t)kt * 4096 + (size_t)p * 2048,
                     sK + (p * 32 + wave * 8) * 64);
            gl_lds16(Vg + (size_t)kt * 64 + (size_t)p * 32 * 1024,
                     sV + (p * 32 + wave * 8) * 64);
        }
        __syncthreads();

        floatx4 s[4];
#pragma unroll
        for (int nt = 0; nt < 4; ++nt) {
            const int r = nt * 16 + l15;
            const int c0 = quad ^ (r & 7);
            const int c1 = (4 + quad) ^ (r & 7);
            const shortx8 kf0 = *(const shortx8*)&sK[r * 64 + c0 * 8];
            const shortx8 kf1 = *(const shortx8*)&sK[r * 64 + c1 * 8];
            floatx4 z = {};
            z = __builtin_amdgcn_mfma_f32_16x16x32_bf16(qf0, kf0, z, 0, 0, 0);
            z = __builtin_amdgcn_mfma_f32_16x16x32_bf16(qf1, kf1, z, 0, 0, 0);
            s[nt] = z;
        }
#pragma unroll
        for (int nt = 0; nt < 4; ++nt)
#pragma unroll
            for (int r = 0; r < 4; ++r) {
                float sv = s[nt][r] * SC;
                if (kt == qb) {
                    const int col = nt * 16 + l15;
                    const int row = wave * 16 + quad * 4 + r;
                    if (col > row) sv = -__builtin_inff();
                }
                s[nt][r] = sv;
            }
        float mnew[4], alpha[4];
#pragma unroll
        for (int r = 0; r < 4; ++r) {
            float mt = fmaxf(fmaxf(s[0][r], s[1][r]), fmaxf(s[2][r], s[3][r]));
#pragma unroll
            for (int o = 8; o >= 1; o >>= 1) mt = fmaxf(mt, __shfl_xor(mt, o, 64));
            mnew[r]  = fmaxf(mstate[r], mt);
            alpha[r] = exp2f(mstate[r] - mnew[r]);
            mstate[r] = mnew[r];
        }
#pragma unroll
        for (int r = 0; r < 4; ++r) {
            float rs = 0.0f;
#pragma unroll
            for (int nt = 0; nt < 4; ++nt) {
                const float p = exp2f(s[nt][r] - mnew[r]);
                s[nt][r] = p;
                rs += p;
            }
#pragma unroll
            for (int o = 8; o >= 1; o >>= 1) rs += __shfl_xor(rs, o, 64);
            lstate[r] = alpha[r] * lstate[r] + rs;
#pragma unroll
            for (int dt = 0; dt < 4; ++dt) oacc[dt][r] *= alpha[r];
        }
#pragma unroll
        for (int nt = 0; nt < 4; ++nt)
#pragma unroll
            for (int r = 0; r < 4; ++r)
                sP[wave][(quad * 4 + r) * 72 + nt * 16 + l15] = f2b(s[nt][r]);
        __asm__ volatile("s_waitcnt lgkmcnt(0)" ::: "memory");
        const shortx8 pf0 = *(const shortx8*)&sP[wave][l15 * 72 + quad * 8];
        const shortx8 pf1 = *(const shortx8*)&sP[wave][l15 * 72 + 32 + quad * 8];
#pragma unroll
        for (int dt = 0; dt < 4; ++dt) {
            const int r = dt * 16 + l15;
            const int c0 = quad ^ (r & 7);
            const int c1 = (4 + quad) ^ (r & 7);
            const shortx8 v0 = *(const shortx8*)&sV[r * 64 + c0 * 8];
            const shortx8 v1 = *(const shortx8*)&sV[r * 64 + c1 * 8];
            oacc[dt] = __builtin_amdgcn_mfma_f32_16x16x32_bf16(pf0, v0, oacc[dt], 0, 0, 0);
            oacc[dt] = __builtin_amdgcn_mfma_f32_16x16x32_bf16(pf1, v1, oacc[dt], 0, 0, 0);
        }
    }
#pragma unroll
    for (int dt = 0; dt < 4; ++dt)
#pragma unroll
        for (int r = 0; r < 4; ++r) {
            const int t = qb * 64 + wave * 16 + quad * 4 + r;
            const int dim = dt * 16 + l15;
            const float v = oacc[dt][r] / lstate[r];
            ctx[(size_t)(bb * 1024 + t) * 1024 + h * 64 + dim] = f2b(v);
        }
}

// ---------------------------------------------------------------------------
// Launch
// ---------------------------------------------------------------------------
extern "C" void kernel_launch(void* const* d_in, const int* in_sizes, int n_in,
                              void* d_out, int out_size, void* d_ws, size_t ws_size,
                              hipStream_t stream) {
    const float* x    = (const float*)d_in[0];
    const float* ln1w = (const float*)d_in[2];
    const float* ln1b = (const float*)d_in[3];
    const float* ln2w = (const float*)d_in[4];
    const float* ln2b = (const float*)d_in[5];
    const float* wq   = (const float*)d_in[6];
    const float* bq   = (const float*)d_in[7];
    const float* wk   = (const float*)d_in[8];
    const float* bk   = (const float*)d_in[9];
    const float* wv   = (const float*)d_in[10];
    const float* bv   = (const float*)d_in[11];
    const float* wo   = (const float*)d_in[12];
    const float* bo   = (const float*)d_in[13];
    const float* w1   = (const float*)d_in[14];
    const float* b1   = (const float*)d_in[15];
    const float* w2   = (const float*)d_in[16];
    const float* b2   = (const float*)d_in[17];

    char* ws = (char*)d_ws;
    const size_t MB = 1024 * 1024;
    ushort* WQKVT = (ushort*)(ws + 0 * MB);     // [3072][1024] bf16 (wq|wk|wv ^T)
    ushort* WOT   = (ushort*)(ws + 6 * MB);     // [1024][1024]
    ushort* W1T   = (ushort*)(ws + 8 * MB);     // [4096][1024]
    ushort* W2T   = (ushort*)(ws + 16 * MB);    // [1024][4096]
    ushort* H1    = (ushort*)(ws + 24 * MB);    // [8192][1024]; H2 overlays later
    ushort* H2    = H1;
    ushort* Qb    = (ushort*)(ws + 40 * MB);    // [128][1024][64]
    ushort* Kb    = (ushort*)(ws + 56 * MB);    // [128][1024][64]
    ushort* Vbt   = (ushort*)(ws + 72 * MB);    // [128][64][1024]
    ushort* FF1   = (ushort*)(ws + 40 * MB);    // [8192][4096] overlays Q,K,V (dead)
    ushort* CTX   = (ushort*)(ws + 104 * MB);   // [8192][1024]

    float* xout = (float*)d_out;                // x2 lives here, then final out

    const dim3 tb(32, 8);
    transp4_kernel<<<dim3(32, 32, 4), tb, 0, stream>>>(
        wq, wk, wv, wo,
        WQKVT, WQKVT + 1024 * 1024, WQKVT + 2048 * 1024, WOT);
    transp_kernel<<<dim3(128, 32), tb, 0, stream>>>(w1, W1T, 1024, 4096);
    transp_kernel<<<dim3(32, 128), tb, 0, stream>>>(w2, W2T, 4096, 1024);

    ln_kernel<<<8192, 256, 0, stream>>>(x, ln1w, ln1b, H1);

    gemm8<1><<<dim3(12, 32), 512, 0, stream>>>(H1, WQKVT, bq, bk, bv,
                                               Qb, Kb, Vbt, 3072, 1024);

    attn_kernel<<<2048, 256, 0, stream>>>(Qb, Kb, Vbt, CTX);

    gemm8r<<<dim3(8, 32), 512, 0, stream>>>(CTX, WOT, bo, xout, x, 1024, 1024);

    ln_kernel<<<8192, 256, 0, stream>>>(xout, ln2w, ln2b, H2);

    gemm8<3><<<dim3(16, 32), 512, 0, stream>>>(H2, W1T, b1, nullptr, nullptr,
                                               FF1, nullptr, nullptr, 4096, 1024);

    gemm8r<<<dim3(8, 32), 512, 0, stream>>>(FF1, W2T, b2, xout, xout, 1024, 4096);

    (void)in_sizes; (void)n_in; (void)out_size; (void)ws_size;
}